// Round 8
// baseline (86.677 us; speedup 1.0000x reference)
//
#include <hip/hip_runtime.h>

// Problem constants (match reference)
#define NS 6
#define NC 64
#define HF 44
#define WF 80
#define HW (HF * WF)       // 3520
#define NZ 16
#define NY 100
#define NX 100
#define XYZ (NX * NY * NZ) // 160000

typedef float v4f __attribute__((ext_vector_type(4)));  // nontemporal store type

// ---------------------------------------------------------------------------
// Camera matrix composition (rows 0..2 of pix_T_cam0 + z_cam row) -> 16 floats
// per camera. Exactly mirrors reference fp32 composition order.
// ---------------------------------------------------------------------------
__device__ void compute_mats(int s, const float* __restrict__ pix,
                             const float* __restrict__ c0TX,
                             float* __restrict__ mats) {
    const float* T = c0TX + s * 16;
    float inv[4][4];
    for (int i = 0; i < 3; ++i) {
        for (int j = 0; j < 3; ++j) inv[i][j] = T[j * 4 + i];
        inv[i][3] = -(T[0 * 4 + i] * T[0 * 4 + 3] +
                      T[1 * 4 + i] * T[1 * 4 + 3] +
                      T[2 * 4 + i] * T[2 * 4 + 3]);
    }
    inv[3][0] = 0.f; inv[3][1] = 0.f; inv[3][2] = 0.f; inv[3][3] = 1.f;
    const float sx = (float)WF / 640.0f;
    const float sy = (float)HF / 352.0f;
    const float* K = pix + s * 16;
    float fp[3][4];
    for (int j = 0; j < 4; ++j) {
        fp[0][j] = sx * K[0 * 4 + j];
        fp[1][j] = sy * K[1 * 4 + j];
        fp[2][j] = K[2 * 4 + j];
    }
    float* M = mats + s * 16;
    for (int i = 0; i < 3; ++i)
        for (int j = 0; j < 4; ++j) {
            float acc = 0.f;
            for (int k = 0; k < 4; ++k) acc += fp[i][k] * inv[k][j];
            M[i * 4 + j] = acc;
        }
    for (int j = 0; j < 4; ++j) M[12 + j] = inv[2][j];
}

// ---------------------------------------------------------------------------
// Kernel 1: transpose features (S,C,HF,WF) -> (S,HF*WF,C); block 0 also
// composes the camera matrices into ws (fused).
// ---------------------------------------------------------------------------
__global__ __launch_bounds__(256) void transpose_feat(
        const float* __restrict__ in, float* __restrict__ outT,
        const float* __restrict__ pix, const float* __restrict__ c0TX,
        float* __restrict__ mats) {
    __shared__ float tile[64 * 65];
    int b = blockIdx.x;
    int t = threadIdx.x;
    if (b == 0 && t < NS) compute_mats(t, pix, c0TX, mats);
    int s = b / 55;
    int hw0 = (b % 55) * 64;
#pragma unroll
    for (int i = 0; i < 4; ++i) {
        int e = t + i * 256;
        int c = e >> 4, wg = e & 15;
        float4 f = *(const float4*)(in + ((size_t)(s * NC + c)) * HW + hw0 + wg * 4);
        tile[c * 65 + wg * 4 + 0] = f.x;
        tile[c * 65 + wg * 4 + 1] = f.y;
        tile[c * 65 + wg * 4 + 2] = f.z;
        tile[c * 65 + wg * 4 + 3] = f.w;
    }
    __syncthreads();
#pragma unroll
    for (int i = 0; i < 4; ++i) {
        int e = t + i * 256;
        int hwl = e >> 4, cg = e & 15;
        float4 f;
        f.x = tile[(cg * 4 + 0) * 65 + hwl];
        f.y = tile[(cg * 4 + 1) * 65 + hwl];
        f.z = tile[(cg * 4 + 2) * 65 + hwl];
        f.w = tile[(cg * 4 + 3) * 65 + hwl];
        *(float4*)(outT + ((size_t)s * HW + hw0 + hwl) * NC + cg * 4) = f;
    }
}

// Fallback-path mats kernel (ws too small for featT).
__global__ void setup_mats(const float* __restrict__ pix,
                           const float* __restrict__ c0TX,
                           float* __restrict__ mats) {
    int s = threadIdx.x;
    if (s < NS) compute_mats(s, pix, c0TX, mats);
}

// ---------------------------------------------------------------------------
// Kernel 2: pooling. SINGLE-WAVE blocks (64 threads), one (x,y) column each.
// Rationale: R2-R7 showed volpool is serialization/occupancy-bound, not
// instruction-bound. 1-wave blocks make every __syncthreads an intra-wave
// s_barrier (no cross-wave coupling) and, with LDS trimmed to ~7.4 KB via
// raw/ostage overlay, ~21 independent waves/CU can be resident.
//  A: lanes compute 96 (z,cam) params (grid-stride, 2 passes) -> raw LDS.
//  B: lanes 0..15 compact per-z into contiguous wts_c/offs_c.
//  C: lane=(zrow=t>>4, cg=t&15), loop zq=0..3 (z = zq*4+zrow): pipelined
//     cam loop, float4 gathers, integer counts, sum * rlut[cnt] epilogue.
//  D: ostage (stride 17, overlaid on raw arrays) -> nontemporal float4 out.
// ---------------------------------------------------------------------------
template <bool TRANS>
__global__ __launch_bounds__(64) void volpool(
        const float* __restrict__ feat,
        const float* __restrict__ mats,
        float* __restrict__ out) {
    // Overlay: raw param arrays (phases A/B) share memory with ostage (C/D).
    __shared__ __align__(16) char ubuf[NC * 17 * 4];   // 4352 B
    float4* wts_raw  = (float4*)ubuf;                  // 96*16 = 1536 B
    int4*   offs_raw = (int4*)(ubuf + 1536);           // 1536 B
    int*    vflags   = (int*)(ubuf + 3072);            // 384 B  (3456 total)
    float*  ostage   = (float*)ubuf;                   // 4352 B after B
    __shared__ float4 wts_c[NZ][NS];
    __shared__ int4   offs_c[NZ][NS];
    __shared__ int    nvalid[NZ];
    __shared__ float  rlut[8];

    int t = threadIdx.x;
    int b = blockIdx.x;
    int x = b % NX, y = b / NX;

    // ---- A: per-(z,cam) projection params (96 pairs over 64 lanes) ----
    for (int p = t; p < 96; p += 64) {
        int s = p % NS, z = p / NS;
        const float* M = mats + s * 16;
        float xw = -40.0f + 0.8f * ((float)x + 0.5f);
        float yw = -40.0f + 0.8f * ((float)y + 0.5f);
        float zw = -1.0f + 0.4f * ((float)z + 0.5f);
        float px = M[0] * xw + M[1] * yw + M[2]  * zw + M[3];
        float py = M[4] * xw + M[5] * yw + M[6]  * zw + M[7];
        float pz = M[8] * xw + M[9] * yw + M[10] * zw + M[11];
        float zc = M[12] * xw + M[13] * yw + M[14] * zw + M[15];
        float denom = fmaxf(pz, 1e-6f);
        float xp = px / denom, yp = py / denom;   // exact IEEE: boundary-safe
        bool valid = (xp > -0.5f) & (xp < (float)WF - 0.5f) &
                     (yp > -0.5f) & (yp < (float)HF - 0.5f) & (zc > 0.0f);
        vflags[p] = valid ? 1 : 0;
        if (valid) {
            float xs = xp - 0.5f, ys = yp - 0.5f;
            float x0f = floorf(xs), y0f = floorf(ys);
            float wx1 = xs - x0f, wy1 = ys - y0f;
            float wx0 = 1.f - wx1, wy0 = 1.f - wy1;
            int xi0 = (int)x0f, yi0 = (int)y0f;
            int xi1 = xi0 + 1, yi1 = yi0 + 1;
            bool bx0 = (xi0 >= 0) & (xi0 < WF);
            bool bx1 = (xi1 >= 0) & (xi1 < WF);
            bool by0 = (yi0 >= 0) & (yi0 < HF);
            bool by1 = (yi1 >= 0) & (yi1 < HF);
            int x0c = min(max(xi0, 0), WF - 1);
            int x1c = min(max(xi1, 0), WF - 1);
            int y0c = min(max(yi0, 0), HF - 1);
            int y1c = min(max(yi1, 0), HF - 1);
            float4 w;
            w.x = wx0 * wy0 * (float)(bx0 & by0);
            w.y = wx1 * wy0 * (float)(bx1 & by0);
            w.z = wx0 * wy1 * (float)(bx0 & by1);
            w.w = wx1 * wy1 * (float)(bx1 & by1);
            int p00 = y0c * WF + x0c, p10 = y0c * WF + x1c;
            int p01 = y1c * WF + x0c, p11 = y1c * WF + x1c;
            int4 o;   // BYTE offsets
            if (TRANS) {
                o.x = (s * HW + p00) << 8;   // * NC * 4
                o.y = (s * HW + p10) << 8;
                o.z = (s * HW + p01) << 8;
                o.w = (s * HW + p11) << 8;
            } else {
                o.x = (s * NC * HW + p00) << 2;
                o.y = (s * NC * HW + p10) << 2;
                o.z = (s * NC * HW + p01) << 2;
                o.w = (s * NC * HW + p11) << 2;
            }
            wts_raw[p] = w;
            offs_raw[p] = o;
        }
    }
    if (t < 8) rlut[t] = 1.0f / ((float)t + 1e-6f);
    __syncthreads();   // single-wave: cheap

    // ---- B: order-preserving compaction into contiguous arrays ----
    if (t < NZ) {
        int base = t * NS;
        int n = 0;
        for (int s = 0; s < NS; ++s) {
            if (vflags[base + s]) {
                wts_c[t][n] = wts_raw[base + s];
                offs_c[t][n] = offs_raw[base + s];
                ++n;
            }
        }
        nvalid[t] = n;
    }
    __syncthreads();   // also fences raw-array reads before ostage overlay

    // ---- C: 4 z-rows per lane, pipelined cam loop each ----
    int cg = t & 15, zrow = t >> 4;
    int ch4 = cg << 2;
    const char* fb = (const char*)feat + (TRANS ? (cg << 4) : 0);
#pragma unroll
    for (int zq = 0; zq < 4; ++zq) {
        int z = zq * 4 + zrow;
        float4 sum = make_float4(0.f, 0.f, 0.f, 0.f);
        int cx = 0, cy = 0, cz = 0, cw = 0;
        int nv = nvalid[z];
        if (nv > 0) {
            float4 w = wts_c[z][0];
            int4 o = offs_c[z][0];
            float4 f00, f10, f01, f11;
            if (TRANS) {
                f00 = *(const float4*)(fb + o.x);
                f10 = *(const float4*)(fb + o.y);
                f01 = *(const float4*)(fb + o.z);
                f11 = *(const float4*)(fb + o.w);
            } else {
                const float* fp = (const float*)fb;
                int e00 = o.x >> 2, e10 = o.y >> 2, e01 = o.z >> 2, e11 = o.w >> 2;
                f00.x = fp[e00 + (ch4+0)*HW]; f00.y = fp[e00 + (ch4+1)*HW];
                f00.z = fp[e00 + (ch4+2)*HW]; f00.w = fp[e00 + (ch4+3)*HW];
                f10.x = fp[e10 + (ch4+0)*HW]; f10.y = fp[e10 + (ch4+1)*HW];
                f10.z = fp[e10 + (ch4+2)*HW]; f10.w = fp[e10 + (ch4+3)*HW];
                f01.x = fp[e01 + (ch4+0)*HW]; f01.y = fp[e01 + (ch4+1)*HW];
                f01.z = fp[e01 + (ch4+2)*HW]; f01.w = fp[e01 + (ch4+3)*HW];
                f11.x = fp[e11 + (ch4+0)*HW]; f11.y = fp[e11 + (ch4+1)*HW];
                f11.z = fp[e11 + (ch4+2)*HW]; f11.w = fp[e11 + (ch4+3)*HW];
            }
            for (int j = 1; j < nv; ++j) {
                float4 w2 = wts_c[z][j];
                int4 o2 = offs_c[z][j];
                float4 g00, g10, g01, g11;
                if (TRANS) {
                    g00 = *(const float4*)(fb + o2.x);
                    g10 = *(const float4*)(fb + o2.y);
                    g01 = *(const float4*)(fb + o2.z);
                    g11 = *(const float4*)(fb + o2.w);
                } else {
                    const float* fp = (const float*)fb;
                    int e00 = o2.x >> 2, e10 = o2.y >> 2, e01 = o2.z >> 2, e11 = o2.w >> 2;
                    g00.x = fp[e00 + (ch4+0)*HW]; g00.y = fp[e00 + (ch4+1)*HW];
                    g00.z = fp[e00 + (ch4+2)*HW]; g00.w = fp[e00 + (ch4+3)*HW];
                    g10.x = fp[e10 + (ch4+0)*HW]; g10.y = fp[e10 + (ch4+1)*HW];
                    g10.z = fp[e10 + (ch4+2)*HW]; g10.w = fp[e10 + (ch4+3)*HW];
                    g01.x = fp[e01 + (ch4+0)*HW]; g01.y = fp[e01 + (ch4+1)*HW];
                    g01.z = fp[e01 + (ch4+2)*HW]; g01.w = fp[e01 + (ch4+3)*HW];
                    g11.x = fp[e11 + (ch4+0)*HW]; g11.y = fp[e11 + (ch4+1)*HW];
                    g11.z = fp[e11 + (ch4+2)*HW]; g11.w = fp[e11 + (ch4+3)*HW];
                }
                float vx = w.x * f00.x + w.y * f10.x + w.z * f01.x + w.w * f11.x;
                float vy = w.x * f00.y + w.y * f10.y + w.z * f01.y + w.w * f11.y;
                float vz = w.x * f00.z + w.y * f10.z + w.z * f01.z + w.w * f11.z;
                float vw = w.x * f00.w + w.y * f10.w + w.z * f01.w + w.w * f11.w;
                sum.x += vx; cx += (vx != 0.0f);
                sum.y += vy; cy += (vy != 0.0f);
                sum.z += vz; cz += (vz != 0.0f);
                sum.w += vw; cw += (vw != 0.0f);
                w = w2; f00 = g00; f10 = g10; f01 = g01; f11 = g11;
            }
            float vx = w.x * f00.x + w.y * f10.x + w.z * f01.x + w.w * f11.x;
            float vy = w.x * f00.y + w.y * f10.y + w.z * f01.y + w.w * f11.y;
            float vz = w.x * f00.z + w.y * f10.z + w.z * f01.z + w.w * f11.z;
            float vw = w.x * f00.w + w.y * f10.w + w.z * f01.w + w.w * f11.w;
            sum.x += vx; cx += (vx != 0.0f);
            sum.y += vy; cy += (vy != 0.0f);
            sum.z += vz; cz += (vz != 0.0f);
            sum.w += vw; cw += (vw != 0.0f);
        }
        ostage[(ch4 + 0) * 17 + z] = sum.x * rlut[cx];
        ostage[(ch4 + 1) * 17 + z] = sum.y * rlut[cy];
        ostage[(ch4 + 2) * 17 + z] = sum.z * rlut[cz];
        ostage[(ch4 + 3) * 17 + z] = sum.w * rlut[cw];
    }
    __syncthreads();

    // ---- D: nontemporal coalesced float4 writes: out[((c*NX+x)*NY+y)*NZ+z] ----
#pragma unroll
    for (int i = 0; i < 4; ++i) {
        int e = t + i * 64;           // 0..255
        int c = e >> 2, zq = e & 3;
        v4f v4;
        v4.x = ostage[c * 17 + zq * 4 + 0];
        v4.y = ostage[c * 17 + zq * 4 + 1];
        v4.z = ostage[c * 17 + zq * 4 + 2];
        v4.w = ostage[c * 17 + zq * 4 + 3];
        float* o = out + (size_t)c * XYZ + ((size_t)x * NY + y) * NZ + zq * 4;
        __builtin_nontemporal_store(v4, (v4f*)o);
    }
}

// ---------------------------------------------------------------------------
extern "C" void kernel_launch(void* const* d_in, const int* in_sizes, int n_in,
                              void* d_out, int out_size, void* d_ws, size_t ws_size,
                              hipStream_t stream) {
    const float* features = (const float*)d_in[0];
    const float* pix      = (const float*)d_in[1];
    const float* c0TX     = (const float*)d_in[2];
    float* out   = (float*)d_out;
    float* mats  = (float*)d_ws;                     // 96 floats = 384 B @ ws+0
    float* featT = (float*)((char*)d_ws + 512);      // transposed features
    size_t need = 512 + sizeof(float) * (size_t)NS * HW * NC;

    if (ws_size >= need) {
        hipLaunchKernelGGL(transpose_feat, dim3(NS * 55), dim3(256), 0, stream,
                           features, featT, pix, c0TX, mats);
        hipLaunchKernelGGL((volpool<true>), dim3(NX * NY), dim3(64), 0, stream,
                           featT, mats, out);
    } else {
        hipLaunchKernelGGL(setup_mats, dim3(1), dim3(64), 0, stream,
                           pix, c0TX, mats);
        hipLaunchKernelGGL((volpool<false>), dim3(NX * NY), dim3(64), 0, stream,
                           features, mats, out);
    }
}

// Round 9
// 84.256 us; speedup vs baseline: 1.0287x; 1.0287x over previous
//
#include <hip/hip_runtime.h>

// Problem constants (match reference)
#define NS 6
#define NC 64
#define HF 44
#define WF 80
#define HW (HF * WF)       // 3520
#define NZ 16
#define NY 100
#define NX 100
#define XYZ (NX * NY * NZ) // 160000

typedef float v4f __attribute__((ext_vector_type(4)));  // nontemporal store type

// ---------------------------------------------------------------------------
// Camera matrix composition (rows 0..2 of pix_T_cam0 + z_cam row) -> 16 floats
// per camera. Exactly mirrors reference fp32 composition order.
// ---------------------------------------------------------------------------
__device__ void compute_mats(int s, const float* __restrict__ pix,
                             const float* __restrict__ c0TX,
                             float* __restrict__ mats) {
    const float* T = c0TX + s * 16;
    float inv[4][4];
    for (int i = 0; i < 3; ++i) {
        for (int j = 0; j < 3; ++j) inv[i][j] = T[j * 4 + i];
        inv[i][3] = -(T[0 * 4 + i] * T[0 * 4 + 3] +
                      T[1 * 4 + i] * T[1 * 4 + 3] +
                      T[2 * 4 + i] * T[2 * 4 + 3]);
    }
    inv[3][0] = 0.f; inv[3][1] = 0.f; inv[3][2] = 0.f; inv[3][3] = 1.f;
    const float sx = (float)WF / 640.0f;
    const float sy = (float)HF / 352.0f;
    const float* K = pix + s * 16;
    float fp[3][4];
    for (int j = 0; j < 4; ++j) {
        fp[0][j] = sx * K[0 * 4 + j];
        fp[1][j] = sy * K[1 * 4 + j];
        fp[2][j] = K[2 * 4 + j];
    }
    float* M = mats + s * 16;
    for (int i = 0; i < 3; ++i)
        for (int j = 0; j < 4; ++j) {
            float acc = 0.f;
            for (int k = 0; k < 4; ++k) acc += fp[i][k] * inv[k][j];
            M[i * 4 + j] = acc;
        }
    for (int j = 0; j < 4; ++j) M[12 + j] = inv[2][j];
}

// ---------------------------------------------------------------------------
// Kernel 1: transpose features (S,C,HF,WF) -> (S,HF*WF,C); block 0 also
// composes the camera matrices into ws (fused).
// ---------------------------------------------------------------------------
__global__ __launch_bounds__(256) void transpose_feat(
        const float* __restrict__ in, float* __restrict__ outT,
        const float* __restrict__ pix, const float* __restrict__ c0TX,
        float* __restrict__ mats) {
    __shared__ float tile[64 * 65];
    int b = blockIdx.x;
    int t = threadIdx.x;
    if (b == 0 && t < NS) compute_mats(t, pix, c0TX, mats);
    int s = b / 55;
    int hw0 = (b % 55) * 64;
#pragma unroll
    for (int i = 0; i < 4; ++i) {
        int e = t + i * 256;
        int c = e >> 4, wg = e & 15;
        float4 f = *(const float4*)(in + ((size_t)(s * NC + c)) * HW + hw0 + wg * 4);
        tile[c * 65 + wg * 4 + 0] = f.x;
        tile[c * 65 + wg * 4 + 1] = f.y;
        tile[c * 65 + wg * 4 + 2] = f.z;
        tile[c * 65 + wg * 4 + 3] = f.w;
    }
    __syncthreads();
#pragma unroll
    for (int i = 0; i < 4; ++i) {
        int e = t + i * 256;
        int hwl = e >> 4, cg = e & 15;
        float4 f;
        f.x = tile[(cg * 4 + 0) * 65 + hwl];
        f.y = tile[(cg * 4 + 1) * 65 + hwl];
        f.z = tile[(cg * 4 + 2) * 65 + hwl];
        f.w = tile[(cg * 4 + 3) * 65 + hwl];
        *(float4*)(outT + ((size_t)s * HW + hw0 + hwl) * NC + cg * 4) = f;
    }
}

// Fallback-path mats kernel (ws too small for featT).
__global__ void setup_mats(const float* __restrict__ pix,
                           const float* __restrict__ c0TX,
                           float* __restrict__ mats) {
    int s = threadIdx.x;
    if (s < NS) compute_mats(s, pix, c0TX, mats);
}

// ---------------------------------------------------------------------------
// Kernel 2: pooling. One block per (x,y) column: 16 z x 64 ch. Identical to
// R7 (best: 84.6 us) EXCEPT the block->(x,y) mapping: XCD-locality swizzle.
// Theory: gathers are ~246 MB/launch; without locality, featT lines are
// replicated across all 8 per-XCD L2s and most gathers fall through to the
// Infinity Cache (~14 TB/s shared) -> ~18 us. With b&7 = spatial region
// (50x25 columns), each XCD's gather footprint is ~2 MB (fits 4 MiB L2),
// moving gathers to local L2 (34.5 TB/s aggregate).
// ---------------------------------------------------------------------------
template <bool TRANS>
__global__ __launch_bounds__(256) void volpool(
        const float* __restrict__ feat,
        const float* __restrict__ mats,
        float* __restrict__ out) {
    __shared__ float4 wts_raw[96];
    __shared__ int4   offs_raw[96];
    __shared__ int    vflags[96];
    __shared__ float4 wts_c[NZ][NS];
    __shared__ int4   offs_c[NZ][NS];
    __shared__ int    nvalid[NZ];
    __shared__ float  rlut[8];
    __shared__ float  ostage[NC * 17];

    int t = threadIdx.x;
    int b = blockIdx.x;
    // XCD-locality swizzle: region = b&7 (block->XCD assumed round-robin),
    // 2 x-halves x 4 y-quarters of 50x25 columns each.
    int reg = b & 7;
    int r = b >> 3;                      // 0..1249
    int x = (reg & 1) * 50 + (r % 50);
    int y = (reg >> 1) * 25 + (r / 50);

    // ---- A: per-(z,cam) projection params ----
    if (t < 96) {
        int s = t % NS, z = t / NS;
        const float* M = mats + s * 16;
        float xw = -40.0f + 0.8f * ((float)x + 0.5f);
        float yw = -40.0f + 0.8f * ((float)y + 0.5f);
        float zw = -1.0f + 0.4f * ((float)z + 0.5f);
        float px = M[0] * xw + M[1] * yw + M[2]  * zw + M[3];
        float py = M[4] * xw + M[5] * yw + M[6]  * zw + M[7];
        float pz = M[8] * xw + M[9] * yw + M[10] * zw + M[11];
        float zc = M[12] * xw + M[13] * yw + M[14] * zw + M[15];
        float denom = fmaxf(pz, 1e-6f);
        float xp = px / denom, yp = py / denom;   // exact IEEE: boundary-safe
        bool valid = (xp > -0.5f) & (xp < (float)WF - 0.5f) &
                     (yp > -0.5f) & (yp < (float)HF - 0.5f) & (zc > 0.0f);
        vflags[t] = valid ? 1 : 0;
        if (valid) {
            float xs = xp - 0.5f, ys = yp - 0.5f;
            float x0f = floorf(xs), y0f = floorf(ys);
            float wx1 = xs - x0f, wy1 = ys - y0f;
            float wx0 = 1.f - wx1, wy0 = 1.f - wy1;
            int xi0 = (int)x0f, yi0 = (int)y0f;
            int xi1 = xi0 + 1, yi1 = yi0 + 1;
            bool bx0 = (xi0 >= 0) & (xi0 < WF);
            bool bx1 = (xi1 >= 0) & (xi1 < WF);
            bool by0 = (yi0 >= 0) & (yi0 < HF);
            bool by1 = (yi1 >= 0) & (yi1 < HF);
            int x0c = min(max(xi0, 0), WF - 1);
            int x1c = min(max(xi1, 0), WF - 1);
            int y0c = min(max(yi0, 0), HF - 1);
            int y1c = min(max(yi1, 0), HF - 1);
            float4 w;
            w.x = wx0 * wy0 * (float)(bx0 & by0);
            w.y = wx1 * wy0 * (float)(bx1 & by0);
            w.z = wx0 * wy1 * (float)(bx0 & by1);
            w.w = wx1 * wy1 * (float)(bx1 & by1);
            int p00 = y0c * WF + x0c, p10 = y0c * WF + x1c;
            int p01 = y1c * WF + x0c, p11 = y1c * WF + x1c;
            int4 o;   // BYTE offsets
            if (TRANS) {
                o.x = (s * HW + p00) << 8;   // * NC * 4
                o.y = (s * HW + p10) << 8;
                o.z = (s * HW + p01) << 8;
                o.w = (s * HW + p11) << 8;
            } else {
                o.x = (s * NC * HW + p00) << 2;
                o.y = (s * NC * HW + p10) << 2;
                o.z = (s * NC * HW + p01) << 2;
                o.w = (s * NC * HW + p11) << 2;
            }
            wts_raw[t] = w;
            offs_raw[t] = o;
        }
    }
    if (t >= 96 && t < 104) {          // reciprocal LUT on spare threads
        int k = t - 96;
        rlut[k] = 1.0f / ((float)k + 1e-6f);
    }
    __syncthreads();

    // ---- B: order-preserving compaction into contiguous arrays ----
    if (t < NZ) {
        int base = t * NS;
        int n = 0;
        for (int s = 0; s < NS; ++s) {
            if (vflags[base + s]) {
                wts_c[t][n] = wts_raw[base + s];
                offs_c[t][n] = offs_raw[base + s];
                ++n;
            }
        }
        nvalid[t] = n;
    }
    __syncthreads();

    // ---- C: pipelined gather + bilinear + integer-count accumulate ----
    int cg = t & 15, z = t >> 4;
    int ch4 = cg << 2;
    const char* fb = (const char*)feat + (TRANS ? (cg << 4) : 0);
    float4 sum = make_float4(0.f, 0.f, 0.f, 0.f);
    int cx = 0, cy = 0, cz = 0, cw = 0;
    int nv = nvalid[z];
    if (nv > 0) {
        float4 w = wts_c[z][0];
        int4 o = offs_c[z][0];
        float4 f00, f10, f01, f11;
        if (TRANS) {
            f00 = *(const float4*)(fb + o.x);
            f10 = *(const float4*)(fb + o.y);
            f01 = *(const float4*)(fb + o.z);
            f11 = *(const float4*)(fb + o.w);
        } else {
            const float* fp = (const float*)fb;
            int e00 = o.x >> 2, e10 = o.y >> 2, e01 = o.z >> 2, e11 = o.w >> 2;
            f00.x = fp[e00 + (ch4+0)*HW]; f00.y = fp[e00 + (ch4+1)*HW];
            f00.z = fp[e00 + (ch4+2)*HW]; f00.w = fp[e00 + (ch4+3)*HW];
            f10.x = fp[e10 + (ch4+0)*HW]; f10.y = fp[e10 + (ch4+1)*HW];
            f10.z = fp[e10 + (ch4+2)*HW]; f10.w = fp[e10 + (ch4+3)*HW];
            f01.x = fp[e01 + (ch4+0)*HW]; f01.y = fp[e01 + (ch4+1)*HW];
            f01.z = fp[e01 + (ch4+2)*HW]; f01.w = fp[e01 + (ch4+3)*HW];
            f11.x = fp[e11 + (ch4+0)*HW]; f11.y = fp[e11 + (ch4+1)*HW];
            f11.z = fp[e11 + (ch4+2)*HW]; f11.w = fp[e11 + (ch4+3)*HW];
        }
        for (int j = 1; j < nv; ++j) {
            float4 w2 = wts_c[z][j];
            int4 o2 = offs_c[z][j];
            float4 g00, g10, g01, g11;
            if (TRANS) {
                g00 = *(const float4*)(fb + o2.x);
                g10 = *(const float4*)(fb + o2.y);
                g01 = *(const float4*)(fb + o2.z);
                g11 = *(const float4*)(fb + o2.w);
            } else {
                const float* fp = (const float*)fb;
                int e00 = o2.x >> 2, e10 = o2.y >> 2, e01 = o2.z >> 2, e11 = o2.w >> 2;
                g00.x = fp[e00 + (ch4+0)*HW]; g00.y = fp[e00 + (ch4+1)*HW];
                g00.z = fp[e00 + (ch4+2)*HW]; g00.w = fp[e00 + (ch4+3)*HW];
                g10.x = fp[e10 + (ch4+0)*HW]; g10.y = fp[e10 + (ch4+1)*HW];
                g10.z = fp[e10 + (ch4+2)*HW]; g10.w = fp[e10 + (ch4+3)*HW];
                g01.x = fp[e01 + (ch4+0)*HW]; g01.y = fp[e01 + (ch4+1)*HW];
                g01.z = fp[e01 + (ch4+2)*HW]; g01.w = fp[e01 + (ch4+3)*HW];
                g11.x = fp[e11 + (ch4+0)*HW]; g11.y = fp[e11 + (ch4+1)*HW];
                g11.z = fp[e11 + (ch4+2)*HW]; g11.w = fp[e11 + (ch4+3)*HW];
            }
            float vx = w.x * f00.x + w.y * f10.x + w.z * f01.x + w.w * f11.x;
            float vy = w.x * f00.y + w.y * f10.y + w.z * f01.y + w.w * f11.y;
            float vz = w.x * f00.z + w.y * f10.z + w.z * f01.z + w.w * f11.z;
            float vw = w.x * f00.w + w.y * f10.w + w.z * f01.w + w.w * f11.w;
            sum.x += vx; cx += (vx != 0.0f);
            sum.y += vy; cy += (vy != 0.0f);
            sum.z += vz; cz += (vz != 0.0f);
            sum.w += vw; cw += (vw != 0.0f);
            w = w2; f00 = g00; f10 = g10; f01 = g01; f11 = g11;
        }
        float vx = w.x * f00.x + w.y * f10.x + w.z * f01.x + w.w * f11.x;
        float vy = w.x * f00.y + w.y * f10.y + w.z * f01.y + w.w * f11.y;
        float vz = w.x * f00.z + w.y * f10.z + w.z * f01.z + w.w * f11.z;
        float vw = w.x * f00.w + w.y * f10.w + w.z * f01.w + w.w * f11.w;
        sum.x += vx; cx += (vx != 0.0f);
        sum.y += vy; cy += (vy != 0.0f);
        sum.z += vz; cz += (vz != 0.0f);
        sum.w += vw; cw += (vw != 0.0f);
    }
    ostage[(ch4 + 0) * 17 + z] = sum.x * rlut[cx];
    ostage[(ch4 + 1) * 17 + z] = sum.y * rlut[cy];
    ostage[(ch4 + 2) * 17 + z] = sum.z * rlut[cz];
    ostage[(ch4 + 3) * 17 + z] = sum.w * rlut[cw];
    __syncthreads();

    // ---- D: nontemporal coalesced float4 write: out[((c*NX+x)*NY+y)*NZ+z] ----
    int c = t >> 2, zq = t & 3;
    v4f v4;
    v4.x = ostage[c * 17 + zq * 4 + 0];
    v4.y = ostage[c * 17 + zq * 4 + 1];
    v4.z = ostage[c * 17 + zq * 4 + 2];
    v4.w = ostage[c * 17 + zq * 4 + 3];
    float* o = out + (size_t)c * XYZ + ((size_t)x * NY + y) * NZ + zq * 4;
    __builtin_nontemporal_store(v4, (v4f*)o);
}

// ---------------------------------------------------------------------------
extern "C" void kernel_launch(void* const* d_in, const int* in_sizes, int n_in,
                              void* d_out, int out_size, void* d_ws, size_t ws_size,
                              hipStream_t stream) {
    const float* features = (const float*)d_in[0];
    const float* pix      = (const float*)d_in[1];
    const float* c0TX     = (const float*)d_in[2];
    float* out   = (float*)d_out;
    float* mats  = (float*)d_ws;                     // 96 floats = 384 B @ ws+0
    float* featT = (float*)((char*)d_ws + 512);      // transposed features
    size_t need = 512 + sizeof(float) * (size_t)NS * HW * NC;

    if (ws_size >= need) {
        hipLaunchKernelGGL(transpose_feat, dim3(NS * 55), dim3(256), 0, stream,
                           features, featT, pix, c0TX, mats);
        hipLaunchKernelGGL((volpool<true>), dim3(NX * NY), dim3(256), 0, stream,
                           featT, mats, out);
    } else {
        hipLaunchKernelGGL(setup_mats, dim3(1), dim3(64), 0, stream,
                           pix, c0TX, mats);
        hipLaunchKernelGGL((volpool<false>), dim3(NX * NY), dim3(256), 0, stream,
                           features, mats, out);
    }
}

// Round 10
// 82.875 us; speedup vs baseline: 1.0459x; 1.0167x over previous
//
#include <hip/hip_runtime.h>
#include <hip/hip_fp16.h>

// Problem constants (match reference)
#define NS 6
#define NC 64
#define HF 44
#define WF 80
#define HW (HF * WF)       // 3520
#define NZ 16
#define NY 100
#define NX 100
#define XYZ (NX * NY * NZ) // 160000

typedef float v4f __attribute__((ext_vector_type(4)));  // nontemporal store type

// Load 4 consecutive fp16 values (8 B) and widen to float4.
__device__ inline float4 ldh4(const char* p) {
    uint2 r = *(const uint2*)p;
    __half2 h0 = *(const __half2*)&r.x;
    __half2 h1 = *(const __half2*)&r.y;
    float2 f0 = __half22float2(h0);
    float2 f1 = __half22float2(h1);
    return make_float4(f0.x, f0.y, f1.x, f1.y);
}

// ---------------------------------------------------------------------------
// Camera matrix composition (rows 0..2 of pix_T_cam0 + z_cam row) -> 16 floats
// per camera. Exactly mirrors reference fp32 composition order.
// ---------------------------------------------------------------------------
__device__ void compute_mats(int s, const float* __restrict__ pix,
                             const float* __restrict__ c0TX,
                             float* __restrict__ mats) {
    const float* T = c0TX + s * 16;
    float inv[4][4];
    for (int i = 0; i < 3; ++i) {
        for (int j = 0; j < 3; ++j) inv[i][j] = T[j * 4 + i];
        inv[i][3] = -(T[0 * 4 + i] * T[0 * 4 + 3] +
                      T[1 * 4 + i] * T[1 * 4 + 3] +
                      T[2 * 4 + i] * T[2 * 4 + 3]);
    }
    inv[3][0] = 0.f; inv[3][1] = 0.f; inv[3][2] = 0.f; inv[3][3] = 1.f;
    const float sx = (float)WF / 640.0f;
    const float sy = (float)HF / 352.0f;
    const float* K = pix + s * 16;
    float fp[3][4];
    for (int j = 0; j < 4; ++j) {
        fp[0][j] = sx * K[0 * 4 + j];
        fp[1][j] = sy * K[1 * 4 + j];
        fp[2][j] = K[2 * 4 + j];
    }
    float* M = mats + s * 16;
    for (int i = 0; i < 3; ++i)
        for (int j = 0; j < 4; ++j) {
            float acc = 0.f;
            for (int k = 0; k < 4; ++k) acc += fp[i][k] * inv[k][j];
            M[i * 4 + j] = acc;
        }
    for (int j = 0; j < 4; ++j) M[12 + j] = inv[2][j];
}

// ---------------------------------------------------------------------------
// Kernel 1: transpose features (S,C,HF,WF) fp32 -> (S,HF*WF,C) fp16.
// Halves the volpool gather traffic (246 -> 123 MB) and makes featT 2.7 MB
// (L2-resident per XCD with the spatial swizzle). Accumulation stays fp32;
// fp16 feature rounding (~2^-11 rel) is far under the 0.09 threshold.
// Block 0 also composes the camera matrices into ws (fused).
// ---------------------------------------------------------------------------
__global__ __launch_bounds__(256) void transpose_feat(
        const float* __restrict__ in, unsigned short* __restrict__ outT,
        const float* __restrict__ pix, const float* __restrict__ c0TX,
        float* __restrict__ mats) {
    __shared__ float tile[64 * 65];
    int b = blockIdx.x;
    int t = threadIdx.x;
    if (b == 0 && t < NS) compute_mats(t, pix, c0TX, mats);
    int s = b / 55;
    int hw0 = (b % 55) * 64;
#pragma unroll
    for (int i = 0; i < 4; ++i) {
        int e = t + i * 256;
        int c = e >> 4, wg = e & 15;
        float4 f = *(const float4*)(in + ((size_t)(s * NC + c)) * HW + hw0 + wg * 4);
        tile[c * 65 + wg * 4 + 0] = f.x;
        tile[c * 65 + wg * 4 + 1] = f.y;
        tile[c * 65 + wg * 4 + 2] = f.z;
        tile[c * 65 + wg * 4 + 3] = f.w;
    }
    __syncthreads();
#pragma unroll
    for (int i = 0; i < 4; ++i) {
        int e = t + i * 256;
        int hwl = e >> 4, cg = e & 15;
        ushort4 h;
        h.x = __half_as_ushort(__float2half_rn(tile[(cg * 4 + 0) * 65 + hwl]));
        h.y = __half_as_ushort(__float2half_rn(tile[(cg * 4 + 1) * 65 + hwl]));
        h.z = __half_as_ushort(__float2half_rn(tile[(cg * 4 + 2) * 65 + hwl]));
        h.w = __half_as_ushort(__float2half_rn(tile[(cg * 4 + 3) * 65 + hwl]));
        *(ushort4*)(outT + ((size_t)s * HW + hw0 + hwl) * NC + cg * 4) = h;
    }
}

// Fallback-path mats kernel (ws too small for featT).
__global__ void setup_mats(const float* __restrict__ pix,
                           const float* __restrict__ c0TX,
                           float* __restrict__ mats) {
    int s = threadIdx.x;
    if (s < NS) compute_mats(s, pix, c0TX, mats);
}

// ---------------------------------------------------------------------------
// Kernel 2: pooling. One block per (x,y) column: 16 z x 64 ch. R7/R9
// structure; TRANS path gathers fp16 (8 B/lane/corner) and widens to fp32.
// XCD-locality swizzle: b&7 -> one of 8 spatial regions (50x25 columns);
// with fp16 featT each XCD's gather footprint ~1.4 MB -> local-L2 resident.
// ---------------------------------------------------------------------------
template <bool TRANS>
__global__ __launch_bounds__(256) void volpool(
        const void* __restrict__ featv,
        const float* __restrict__ mats,
        float* __restrict__ out) {
    __shared__ float4 wts_raw[96];
    __shared__ int4   offs_raw[96];
    __shared__ int    vflags[96];
    __shared__ float4 wts_c[NZ][NS];
    __shared__ int4   offs_c[NZ][NS];
    __shared__ int    nvalid[NZ];
    __shared__ float  rlut[8];
    __shared__ float  ostage[NC * 17];

    int t = threadIdx.x;
    int b = blockIdx.x;
    int reg = b & 7;
    int r = b >> 3;                      // 0..1249
    int x = (reg & 1) * 50 + (r % 50);
    int y = (reg >> 1) * 25 + (r / 50);

    // ---- A: per-(z,cam) projection params ----
    if (t < 96) {
        int s = t % NS, z = t / NS;
        const float* M = mats + s * 16;
        float xw = -40.0f + 0.8f * ((float)x + 0.5f);
        float yw = -40.0f + 0.8f * ((float)y + 0.5f);
        float zw = -1.0f + 0.4f * ((float)z + 0.5f);
        float px = M[0] * xw + M[1] * yw + M[2]  * zw + M[3];
        float py = M[4] * xw + M[5] * yw + M[6]  * zw + M[7];
        float pz = M[8] * xw + M[9] * yw + M[10] * zw + M[11];
        float zc = M[12] * xw + M[13] * yw + M[14] * zw + M[15];
        float denom = fmaxf(pz, 1e-6f);
        float xp = px / denom, yp = py / denom;   // exact IEEE: boundary-safe
        bool valid = (xp > -0.5f) & (xp < (float)WF - 0.5f) &
                     (yp > -0.5f) & (yp < (float)HF - 0.5f) & (zc > 0.0f);
        vflags[t] = valid ? 1 : 0;
        if (valid) {
            float xs = xp - 0.5f, ys = yp - 0.5f;
            float x0f = floorf(xs), y0f = floorf(ys);
            float wx1 = xs - x0f, wy1 = ys - y0f;
            float wx0 = 1.f - wx1, wy0 = 1.f - wy1;
            int xi0 = (int)x0f, yi0 = (int)y0f;
            int xi1 = xi0 + 1, yi1 = yi0 + 1;
            bool bx0 = (xi0 >= 0) & (xi0 < WF);
            bool bx1 = (xi1 >= 0) & (xi1 < WF);
            bool by0 = (yi0 >= 0) & (yi0 < HF);
            bool by1 = (yi1 >= 0) & (yi1 < HF);
            int x0c = min(max(xi0, 0), WF - 1);
            int x1c = min(max(xi1, 0), WF - 1);
            int y0c = min(max(yi0, 0), HF - 1);
            int y1c = min(max(yi1, 0), HF - 1);
            float4 w;
            w.x = wx0 * wy0 * (float)(bx0 & by0);
            w.y = wx1 * wy0 * (float)(bx1 & by0);
            w.z = wx0 * wy1 * (float)(bx0 & by1);
            w.w = wx1 * wy1 * (float)(bx1 & by1);
            int p00 = y0c * WF + x0c, p10 = y0c * WF + x1c;
            int p01 = y1c * WF + x0c, p11 = y1c * WF + x1c;
            int4 o;   // BYTE offsets
            if (TRANS) {
                o.x = (s * HW + p00) << 7;   // * NC * 2 (fp16)
                o.y = (s * HW + p10) << 7;
                o.z = (s * HW + p01) << 7;
                o.w = (s * HW + p11) << 7;
            } else {
                o.x = (s * NC * HW + p00) << 2;
                o.y = (s * NC * HW + p10) << 2;
                o.z = (s * NC * HW + p01) << 2;
                o.w = (s * NC * HW + p11) << 2;
            }
            wts_raw[t] = w;
            offs_raw[t] = o;
        }
    }
    if (t >= 96 && t < 104) {          // reciprocal LUT on spare threads
        int k = t - 96;
        rlut[k] = 1.0f / ((float)k + 1e-6f);
    }
    __syncthreads();

    // ---- B: order-preserving compaction into contiguous arrays ----
    if (t < NZ) {
        int base = t * NS;
        int n = 0;
        for (int s = 0; s < NS; ++s) {
            if (vflags[base + s]) {
                wts_c[t][n] = wts_raw[base + s];
                offs_c[t][n] = offs_raw[base + s];
                ++n;
            }
        }
        nvalid[t] = n;
    }
    __syncthreads();

    // ---- C: pipelined gather + bilinear + integer-count accumulate ----
    int cg = t & 15, z = t >> 4;
    int ch4 = cg << 2;
    const char* fb = (const char*)featv + (TRANS ? (cg << 3) : 0);
    float4 sum = make_float4(0.f, 0.f, 0.f, 0.f);
    int cx = 0, cy = 0, cz = 0, cw = 0;
    int nv = nvalid[z];
    if (nv > 0) {
        float4 w = wts_c[z][0];
        int4 o = offs_c[z][0];
        float4 f00, f10, f01, f11;
        if (TRANS) {
            f00 = ldh4(fb + o.x);
            f10 = ldh4(fb + o.y);
            f01 = ldh4(fb + o.z);
            f11 = ldh4(fb + o.w);
        } else {
            const float* fp = (const float*)fb;
            int e00 = o.x >> 2, e10 = o.y >> 2, e01 = o.z >> 2, e11 = o.w >> 2;
            f00.x = fp[e00 + (ch4+0)*HW]; f00.y = fp[e00 + (ch4+1)*HW];
            f00.z = fp[e00 + (ch4+2)*HW]; f00.w = fp[e00 + (ch4+3)*HW];
            f10.x = fp[e10 + (ch4+0)*HW]; f10.y = fp[e10 + (ch4+1)*HW];
            f10.z = fp[e10 + (ch4+2)*HW]; f10.w = fp[e10 + (ch4+3)*HW];
            f01.x = fp[e01 + (ch4+0)*HW]; f01.y = fp[e01 + (ch4+1)*HW];
            f01.z = fp[e01 + (ch4+2)*HW]; f01.w = fp[e01 + (ch4+3)*HW];
            f11.x = fp[e11 + (ch4+0)*HW]; f11.y = fp[e11 + (ch4+1)*HW];
            f11.z = fp[e11 + (ch4+2)*HW]; f11.w = fp[e11 + (ch4+3)*HW];
        }
        for (int j = 1; j < nv; ++j) {
            float4 w2 = wts_c[z][j];
            int4 o2 = offs_c[z][j];
            float4 g00, g10, g01, g11;
            if (TRANS) {
                g00 = ldh4(fb + o2.x);
                g10 = ldh4(fb + o2.y);
                g01 = ldh4(fb + o2.z);
                g11 = ldh4(fb + o2.w);
            } else {
                const float* fp = (const float*)fb;
                int e00 = o2.x >> 2, e10 = o2.y >> 2, e01 = o2.z >> 2, e11 = o2.w >> 2;
                g00.x = fp[e00 + (ch4+0)*HW]; g00.y = fp[e00 + (ch4+1)*HW];
                g00.z = fp[e00 + (ch4+2)*HW]; g00.w = fp[e00 + (ch4+3)*HW];
                g10.x = fp[e10 + (ch4+0)*HW]; g10.y = fp[e10 + (ch4+1)*HW];
                g10.z = fp[e10 + (ch4+2)*HW]; g10.w = fp[e10 + (ch4+3)*HW];
                g01.x = fp[e01 + (ch4+0)*HW]; g01.y = fp[e01 + (ch4+1)*HW];
                g01.z = fp[e01 + (ch4+2)*HW]; g01.w = fp[e01 + (ch4+3)*HW];
                g11.x = fp[e11 + (ch4+0)*HW]; g11.y = fp[e11 + (ch4+1)*HW];
                g11.z = fp[e11 + (ch4+2)*HW]; g11.w = fp[e11 + (ch4+3)*HW];
            }
            float vx = w.x * f00.x + w.y * f10.x + w.z * f01.x + w.w * f11.x;
            float vy = w.x * f00.y + w.y * f10.y + w.z * f01.y + w.w * f11.y;
            float vz = w.x * f00.z + w.y * f10.z + w.z * f01.z + w.w * f11.z;
            float vw = w.x * f00.w + w.y * f10.w + w.z * f01.w + w.w * f11.w;
            sum.x += vx; cx += (vx != 0.0f);
            sum.y += vy; cy += (vy != 0.0f);
            sum.z += vz; cz += (vz != 0.0f);
            sum.w += vw; cw += (vw != 0.0f);
            w = w2; f00 = g00; f10 = g10; f01 = g01; f11 = g11;
        }
        float vx = w.x * f00.x + w.y * f10.x + w.z * f01.x + w.w * f11.x;
        float vy = w.x * f00.y + w.y * f10.y + w.z * f01.y + w.w * f11.y;
        float vz = w.x * f00.z + w.y * f10.z + w.z * f01.z + w.w * f11.z;
        float vw = w.x * f00.w + w.y * f10.w + w.z * f01.w + w.w * f11.w;
        sum.x += vx; cx += (vx != 0.0f);
        sum.y += vy; cy += (vy != 0.0f);
        sum.z += vz; cz += (vz != 0.0f);
        sum.w += vw; cw += (vw != 0.0f);
    }
    ostage[(ch4 + 0) * 17 + z] = sum.x * rlut[cx];
    ostage[(ch4 + 1) * 17 + z] = sum.y * rlut[cy];
    ostage[(ch4 + 2) * 17 + z] = sum.z * rlut[cz];
    ostage[(ch4 + 3) * 17 + z] = sum.w * rlut[cw];
    __syncthreads();

    // ---- D: nontemporal coalesced float4 write: out[((c*NX+x)*NY+y)*NZ+z] ----
    int c = t >> 2, zq = t & 3;
    v4f v4;
    v4.x = ostage[c * 17 + zq * 4 + 0];
    v4.y = ostage[c * 17 + zq * 4 + 1];
    v4.z = ostage[c * 17 + zq * 4 + 2];
    v4.w = ostage[c * 17 + zq * 4 + 3];
    float* o = out + (size_t)c * XYZ + ((size_t)x * NY + y) * NZ + zq * 4;
    __builtin_nontemporal_store(v4, (v4f*)o);
}

// ---------------------------------------------------------------------------
extern "C" void kernel_launch(void* const* d_in, const int* in_sizes, int n_in,
                              void* d_out, int out_size, void* d_ws, size_t ws_size,
                              hipStream_t stream) {
    const float* features = (const float*)d_in[0];
    const float* pix      = (const float*)d_in[1];
    const float* c0TX     = (const float*)d_in[2];
    float* out   = (float*)d_out;
    float* mats  = (float*)d_ws;                            // 384 B @ ws+0
    unsigned short* featT = (unsigned short*)((char*)d_ws + 512);  // fp16 featT
    size_t need = 512 + sizeof(unsigned short) * (size_t)NS * HW * NC;

    if (ws_size >= need) {
        hipLaunchKernelGGL(transpose_feat, dim3(NS * 55), dim3(256), 0, stream,
                           features, featT, pix, c0TX, mats);
        hipLaunchKernelGGL((volpool<true>), dim3(NX * NY), dim3(256), 0, stream,
                           (const void*)featT, mats, out);
    } else {
        hipLaunchKernelGGL(setup_mats, dim3(1), dim3(64), 0, stream,
                           pix, c0TX, mats);
        hipLaunchKernelGGL((volpool<false>), dim3(NX * NY), dim3(256), 0, stream,
                           (const void*)features, mats, out);
    }
}